// Round 6
// baseline (9521.942 us; speedup 1.0000x reference)
//
#include <hip/hip_runtime.h>
#include <math.h>

#define BSZ 512
#define SEQ 128
#define FF  136
#define HH  128

// ---------------- transpose (384x128 -> 128x384) ----------------
__global__ __launch_bounds__(256) void k_transpose384(const float* __restrict__ A,
                                                      float* __restrict__ At) {
    int i = blockIdx.x * 256 + threadIdx.x;          // over 384*128
    if (i < 384 * 128) {
        int r = i >> 7, c = i & 127;
        At[c * 384 + r] = A[i];
    }
}

// ---------------- fused doc FNN + V + GI + SV precompute ----------------
__global__ __launch_bounds__(256) void k_docvgi(
    const float* __restrict__ br,
    const float* __restrict__ fW1, const float* __restrict__ fb1,
    const float* __restrict__ fW2, const float* __restrict__ fb2,
    const float* __restrict__ comW1,
    const float* __restrict__ WihT, const float* __restrict__ bih,
    const float* __restrict__ cntW1,
    float* __restrict__ V, float* __restrict__ GI, float* __restrict__ SV)
{
    __shared__ float xs[32][FF];
    __shared__ float hs[32][HH];
    __shared__ float ds[32][HH];
    int row0 = blockIdx.x * 32;
    int t = threadIdx.x;
    const float* src = br + (size_t)row0 * FF;
    for (int i = t; i < 32 * FF; i += 256) xs[i / FF][i % FF] = src[i];
    __syncthreads();
    int j = t & 127, rg = t >> 7;
    float acc[16];
#pragma unroll
    for (int r = 0; r < 16; r++) acc[r] = 0.f;
    for (int k = 0; k < FF; k++) {
        float w = fW1[k * HH + j];
#pragma unroll
        for (int r = 0; r < 16; r++) acc[r] += xs[rg + 2 * r][k] * w;
    }
    {
        float bb = fb1[j];
#pragma unroll
        for (int r = 0; r < 16; r++) hs[rg + 2 * r][j] = fmaxf(acc[r] + bb, 0.f);
    }
    __syncthreads();
#pragma unroll
    for (int r = 0; r < 16; r++) acc[r] = 0.f;
    for (int k = 0; k < HH; k++) {
        float w = fW2[k * HH + j];
#pragma unroll
        for (int r = 0; r < 16; r++) acc[r] += hs[rg + 2 * r][k] * w;
    }
    {
        float bb = fb2[j];
#pragma unroll
        for (int r = 0; r < 16; r++)
            ds[rg + 2 * r][j] = 1.f / (1.f + expf(-(acc[r] + bb)));
    }
    __syncthreads();
#pragma unroll
    for (int r = 0; r < 16; r++) acc[r] = 0.f;
    for (int k = 0; k < HH; k++) {
        float w = comW1[k * HH + j];
#pragma unroll
        for (int r = 0; r < 16; r++) acc[r] += ds[rg + 2 * r][k] * w;
    }
#pragma unroll
    for (int r = 0; r < 16; r++) V[(size_t)(row0 + rg + 2 * r) * HH + j] = acc[r];
    for (int p = 0; p < 3; p++) {
        int jj = p * HH + j;
#pragma unroll
        for (int r = 0; r < 16; r++) acc[r] = 0.f;
        for (int k = 0; k < HH; k++) {
            float w = WihT[k * 384 + jj];
#pragma unroll
            for (int r = 0; r < 16; r++) acc[r] += ds[rg + 2 * r][k] * w;
        }
        float bb = bih[jj];
#pragma unroll
        for (int r = 0; r < 16; r++)
            GI[(size_t)(row0 + rg + 2 * r) * 384 + jj] = acc[r] + bb;
    }
    // SV = br @ cntW1[FF:2FF,:]
#pragma unroll
    for (int r = 0; r < 16; r++) acc[r] = 0.f;
    for (int k = 0; k < FF; k++) {
        float w = cntW1[(FF + k) * HH + j];
#pragma unroll
        for (int r = 0; r < 16; r++) acc[r] += xs[rg + 2 * r][k] * w;
    }
#pragma unroll
    for (int r = 0; r < 16; r++) SV[(size_t)(row0 + rg + 2 * r) * HH + j] = acc[r];
}

// ---------------- scan: 1 elem/block, 256 threads, hard VGPR cap for 2 blocks/CU ----------------
__global__ __launch_bounds__(256, 4) void k_scan6(
    const float* __restrict__ br,
    const float* __restrict__ cntW1, const float* __restrict__ cntb1,
    const float* __restrict__ cntW2, const float* __restrict__ cntb2,
    const float* __restrict__ comW1, const float* __restrict__ comb1,
    const float* __restrict__ comW2,
    const float* __restrict__ WhhT, const float* __restrict__ gbhh,
    const float* __restrict__ V, const float* __restrict__ GI,
    const float* __restrict__ SV,
    float* __restrict__ out)
{
    __shared__ float  Vl[SEQ][HH + 1];      // 66 KB, padded -> conflict-free D reads
    __shared__ float  a1S[HH], crS[HH], uS[HH], hS[HH], c2S[HH];
    __shared__ float  pp2[2][HH];           // shared partials for B, C, D (disjoint lifetimes)
    __shared__ float  ppG[6][HH];           // GRU gate partials
    __shared__ float  mxS[FF], chgDl[FF];   // chgDl holds colsum at init
    __shared__ int    mxiS[FF], chgF[FF], maskS[SEQ];
    __shared__ int    selS, chgN;
    // total LDS ~75.4 KB -> 2 blocks/CU

    const int b = blockIdx.x;
    const int t = threadIdx.x;
    const int kh = t >> 7, j = t & 127;
    const float* brB = br + (size_t)b * SEQ * FF;
    const float* GIb = GI + (size_t)b * SEQ * 384;
    const float* SVb = SV + (size_t)b * SEQ * HH;

    // ---- init ----
    {
        const float* Vb = V + (size_t)b * SEQ * HH;
        for (int idx = t; idx < SEQ * HH; idx += 256)
            Vl[idx >> 7][idx & 127] = Vb[idx];
    }
    if (t < HH)  { hS[t] = 0.f; c2S[t] = comW2[t]; }
    if (t < SEQ) maskS[t] = 1;
    if (t < FF) {
        float cs = 0.f; float mx = -__builtin_huge_valf(); int mi = 0;
        const float* bp = brB + t;
        for (int s = 0; s < SEQ; s++) {
            float v = bp[s * FF];
            cs += v;
            if (v > mx) { mx = v; mi = s; }
        }
        mxS[t] = mx; mxiS[t] = mi; chgDl[t] = cs;
    }
    __syncthreads();

    double mxv = 0.0, sv = 0.0;             // per-thread (t<128) fp64 accumulators
    if (t < HH) {
#pragma unroll 2
        for (int f = 0; f < FF; f++) {
            mxv += (double)mxS[f]   * (double)cntW1[f * HH + t];
            sv  += (double)chgDl[f] * (double)cntW1[(FF + f) * HH + t];
        }
        a1S[t] = fmaxf((float)(mxv + sv / 128.0) + cntb1[t], 0.f);
    }
    __syncthreads();

    for (int i = 0; i < SEQ; i++) {
        // ---- B: pp2 = a1 @ cntW2 (k-split2) ----
        {
            const float* W = cntW2 + (size_t)(kh * 64) * HH + j;
            const float* a = a1S + kh * 64;
            float acc = 0.f;
            for (int m = 0; m < 64; m++) acc += a[m] * W[m * HH];
            pp2[kh][j] = acc;
        }
        __syncthreads();

        // ---- cr = sigmoid(.) ; reset chg counter ----
        if (t < HH) crS[t] = 1.f / (1.f + expf(-(pp2[0][t] + pp2[1][t] + cntb2[t])));
        else if (t == HH) chgN = 0;
        __syncthreads();

        // ---- C: u-halves: cr @ comW1[128:256] (kh=0) | h @ comW1[256:384] (kh=1) ----
        {
            const float* W = comW1 + (size_t)(HH + kh * HH) * HH + j;
            const float* s0 = kh ? hS : crS;
            float acc = 0.f;
            for (int m = 0; m < 128; m++) acc += s0[m] * W[m * HH];
            pp2[kh][j] = acc;
        }
        __syncthreads();
        if (t < HH) uS[t] = pp2[0][t] + pp2[1][t] + comb1[t];
        __syncthreads();

        // ---- D: score partials (k-split2, LDS only) ----
        {
            float acc = 0.f;
            const int k0 = kh * 64;
            for (int m = 0; m < 64; m++) {
                int k = k0 + m;
                acc += c2S[k] * fmaxf(Vl[j][k] + uS[k], 0.f);
            }
            pp2[kh][j] = acc;
        }
        __syncthreads();

        // ---- argmax (wave 0), first-index tie break ----
        if (t < 64) {
            float s1 = pp2[0][t] + pp2[1][t];
            float s2 = pp2[0][t + 64] + pp2[1][t + 64];
            float v1 = maskS[t]      ? s1 : -__builtin_huge_valf();
            float v2 = maskS[t + 64] ? s2 : -__builtin_huge_valf();
            float v; int idx;
            if (v2 > v1) { v = v2; idx = t + 64; } else { v = v1; idx = t; }
            for (int off = 32; off >= 1; off >>= 1) {
                float ov = __shfl_down(v, off);
                int   oi = __shfl_down(idx, off);
                if (ov > v || (ov == v && oi < idx)) { v = ov; idx = oi; }
            }
            if (t == 0) {
                selS = idx;
                maskS[idx] = 0;
                out[(size_t)b * SEQ + idx] = powf(0.9f, (float)i);
            }
        }
        __syncthreads();
        const int sel = selS;

        float gr0 = 0.f, gr1 = 0.f, gr2 = 0.f, svp = 0.f;  // GI/SV row prefetch regs

        // ---- P8: stale-max detect (t<136) + GI/SV row prefetch (t<128) ----
        if (i < SEQ - 1) {
            if (t < FF && sel == mxiS[t]) {
                int e = atomicAdd(&chgN, 1);
                chgF[e] = t;
            }
            if (t < HH) {
                const float* gir = GIb + (size_t)sel * 384;
                gr0 = gir[t]; gr1 = gir[HH + t]; gr2 = gir[2 * HH + t];
                svp = SVb[(size_t)sel * HH + t];
            }
        }
        __syncthreads();

        // ---- P9: wave-parallel rescan of changed features ----
        if (i < SEQ - 1) {
            const int w = t >> 6, lane = t & 63;
            const int n = chgN;
#pragma unroll 1
            for (int e = w; e < n; e += 4) {
                int f = chgF[e];
                float om = mxS[f];
                const float* bp = brB + f;
                float v1 = maskS[lane]      ? bp[lane * FF]        : -__builtin_huge_valf();
                float v2 = maskS[lane + 64] ? bp[(lane + 64) * FF] : -__builtin_huge_valf();
                float v; int idx;
                if (v2 > v1) { v = v2; idx = lane + 64; } else { v = v1; idx = lane; }
                for (int off = 32; off >= 1; off >>= 1) {
                    float ov = __shfl_down(v, off);
                    int   oi = __shfl_down(idx, off);
                    if (ov > v || (ov == v && oi < idx)) { v = ov; idx = oi; }
                }
                if (lane == 0) { mxS[f] = v; mxiS[f] = idx; chgDl[e] = v - om; }
            }
        }
        __syncthreads();

        // ---- G: gh partials = h @ WhhT (k-split2, 3 gates) ----
        if (i < SEQ - 1) {
            const float* Wr = WhhT + (size_t)(kh * 64) * 384;
            float ar = 0.f, az = 0.f, an = 0.f;
            for (int m = 0; m < 64; m++) {
                float hv = hS[kh * 64 + m];
                const float* row = Wr + m * 384;
                ar += hv * row[j]; az += hv * row[HH + j]; an += hv * row[2 * HH + j];
            }
            ppG[kh][j] = ar; ppG[2 + kh][j] = az; ppG[4 + kh][j] = an;
        }
        __syncthreads();

        // ---- P10: GRU finish + incremental mxv/sv + next a1 ----
        if (i < SEQ - 1 && t < HH) {
            float ghr = ppG[0][t] + ppG[1][t] + gbhh[t];
            float ghz = ppG[2][t] + ppG[3][t] + gbhh[HH + t];
            float ghn = ppG[4][t] + ppG[5][t] + gbhh[2 * HH + t];
            float rr = 1.f / (1.f + expf(-(gr0 + ghr)));
            float zz = 1.f / (1.f + expf(-(gr1 + ghz)));
            float nn = tanhf(gr2 + rr * ghn);
            hS[t] = (1.f - zz) * nn + zz * hS[t];

            const int n = chgN;
#pragma unroll 2
            for (int e = 0; e < n; e++)
                mxv += (double)chgDl[e] * (double)cntW1[chgF[e] * HH + t];
            sv -= (double)svp;
            a1S[t] = fmaxf((float)(mxv + sv / (double)(SEQ - 1 - i)) + cntb1[t], 0.f);
        }
        __syncthreads();
    }
}

extern "C" void kernel_launch(void* const* d_in, const int* in_sizes, int n_in,
                              void* d_out, int out_size, void* d_ws, size_t ws_size,
                              hipStream_t stream) {
    (void)in_sizes; (void)n_in; (void)out_size; (void)ws_size;
    const float* br    = (const float*)d_in[0];
    const float* fnnW1 = (const float*)d_in[2];
    const float* fnnb1 = (const float*)d_in[3];
    const float* fnnW2 = (const float*)d_in[4];
    const float* fnnb2 = (const float*)d_in[5];
    const float* cntW1 = (const float*)d_in[6];
    const float* cntb1 = (const float*)d_in[7];
    const float* cntW2 = (const float*)d_in[8];
    const float* cntb2 = (const float*)d_in[9];
    const float* comW1 = (const float*)d_in[10];
    const float* comb1 = (const float*)d_in[11];
    const float* comW2 = (const float*)d_in[12];
    const float* Wih   = (const float*)d_in[14];
    const float* Whh   = (const float*)d_in[15];
    const float* bih   = (const float*)d_in[16];
    const float* bhh   = (const float*)d_in[17];

    float* ws   = (float*)d_ws;
    float* V    = ws;                          // 512*128*128 =  8,388,608 f
    float* GI   = V + 8388608;                 // 512*128*384 = 25,165,824 f
    float* SV   = GI + 25165824;               // 512*128*128 =  8,388,608 f
    float* WihT = SV + 8388608;                // 128*384
    float* WhhT = WihT + 49152;                // 128*384

    hipLaunchKernelGGL(k_transpose384, dim3(192), dim3(256), 0, stream, Wih, WihT);
    hipLaunchKernelGGL(k_transpose384, dim3(192), dim3(256), 0, stream, Whh, WhhT);
    hipLaunchKernelGGL(k_docvgi, dim3(2048), dim3(256), 0, stream,
                       br, fnnW1, fnnb1, fnnW2, fnnb2, comW1, WihT, bih, cntW1,
                       V, GI, SV);
    hipLaunchKernelGGL(k_scan6, dim3(BSZ), dim3(256), 0, stream,
                       br, cntW1, cntb1, cntW2, cntb2, comW1, comb1, comW2,
                       WhhT, bhh, V, GI, SV, (float*)d_out);
}